// Round 2
// 360.323 us; speedup vs baseline: 1.0085x; 1.0085x over previous
//
#include <hip/hip_runtime.h>
#include <hip/hip_bf16.h>

typedef __attribute__((ext_vector_type(8))) short short8;       // 8 bf16 (A/B frag)
typedef __attribute__((ext_vector_type(4))) float floatx4;      // C/D frag
typedef __attribute__((ext_vector_type(4))) unsigned short ushort4v;

__device__ inline unsigned short f2bf(float x) {                 // RNE f32->bf16 bits
    unsigned int u = __float_as_uint(x);
    u += 0x7FFFu + ((u >> 16) & 1u);
    return (unsigned short)(u >> 16);
}
__device__ inline float bf2f(unsigned short h) {
    return __uint_as_float(((unsigned int)h) << 16);
}
__device__ inline float blo(unsigned int u) { return __uint_as_float(u << 16); }
__device__ inline float bhi(unsigned int u) { return __uint_as_float(u & 0xFFFF0000u); }

#if defined(__has_builtin)
#if __has_builtin(__builtin_amdgcn_exp2f)
#define EXP2F(x) __builtin_amdgcn_exp2f(x)
#else
#define EXP2F(x) exp2f(x)
#endif
#if __has_builtin(__builtin_amdgcn_update_dpp)
#define HAVE_DPP 1
#endif
#else
#define EXP2F(x) exp2f(x)
#endif

// DPP butterfly add: x + shuffle(x) — pure VALU, no LDS pipe, no lgkmcnt wait.
#ifdef HAVE_DPP
template <int CTRL>
__device__ __forceinline__ float dppadd(float x) {
    int s = __builtin_amdgcn_update_dpp(0, __float_as_int(x), CTRL, 0xf, 0xf, true);
    return x + __int_as_float(s);
}
// sum over the 8 lanes of a g-octet (lane bits 0..2): xor1, xor2, xor7-mirror
__device__ __forceinline__ float red8(float x) {
    x = dppadd<0xB1>(x);    // quad_perm [1,0,3,2]  = xor 1
    x = dppadd<0x4E>(x);    // quad_perm [2,3,0,1]  = xor 2
    x = dppadd<0x141>(x);   // row_half_mirror      = xor 7 (valid: quads uniform)
    return x;
}
__device__ __forceinline__ float xor8add(float x) {
    return dppadd<0x128>(x);   // row_ror:8 = xor 8 within 16-lane row
}
#else
__device__ __forceinline__ float red8(float x) {
    x += __shfl_xor(x, 1); x += __shfl_xor(x, 2); x += __shfl_xor(x, 4);
    return x;
}
__device__ __forceinline__ float xor8add(float x) { return x + __shfl_xor(x, 8); }
#endif

template <bool B> struct BC { static constexpr bool value = B; };

// ---------------- CSR build ----------------
__global__ __launch_bounds__(256) void hist_kernel(
    const int* __restrict__ dst, int* __restrict__ deg, int E)
{
    int e = blockIdx.x * blockDim.x + threadIdx.x;
    if (e < E) atomicAdd(&deg[dst[e]], 1);
}

// hierarchical scan: block sums -> top scan (<=64 blocks) -> add-back
__global__ __launch_bounds__(256) void scan_part(
    const int* __restrict__ deg, int* __restrict__ bsum, int N)
{
    __shared__ int ws[4];
    const int base = blockIdx.x * 1024;
    const int tid = threadIdx.x, lane = tid & 63, w = tid >> 6;
    int s = 0;
#pragma unroll
    for (int j = 0; j < 4; j++) {
        int i = base + j * 256 + tid;
        if (i < N) s += deg[i];
    }
#pragma unroll
    for (int off = 1; off < 64; off <<= 1) s += __shfl_xor(s, off, 64);
    if (lane == 0) ws[w] = s;
    __syncthreads();
    if (tid == 0) bsum[blockIdx.x] = ws[0] + ws[1] + ws[2] + ws[3];
}

__global__ __launch_bounds__(64) void scan_tops(
    const int* __restrict__ bsum, int* __restrict__ boff,
    int* __restrict__ rowptr, int nb, int N)
{
    int lane = threadIdx.x;
    int v = (lane < nb) ? bsum[lane] : 0;
    int inc = v;
#pragma unroll
    for (int off = 1; off < 64; off <<= 1) {
        int t = __shfl_up(inc, off, 64);
        if (lane >= off) inc += t;
    }
    if (lane < nb) boff[lane] = inc - v;
    if (lane == 63) rowptr[N] = inc;
}

__global__ __launch_bounds__(256) void scan_final(
    const int* __restrict__ deg, const int* __restrict__ boff,
    int* __restrict__ rowptr, int* __restrict__ cursor, int N)
{
    __shared__ int woff[4];
    const int base = blockIdx.x * 1024;
    const int tid = threadIdx.x, lane = tid & 63, w = tid >> 6;
    const int i0 = base + tid * 4;
    int v0 = (i0     < N) ? deg[i0]     : 0;
    int v1 = (i0 + 1 < N) ? deg[i0 + 1] : 0;
    int v2 = (i0 + 2 < N) ? deg[i0 + 2] : 0;
    int v3 = (i0 + 3 < N) ? deg[i0 + 3] : 0;
    int ts = v0 + v1 + v2 + v3;
    int inc = ts;
#pragma unroll
    for (int off = 1; off < 64; off <<= 1) {
        int t = __shfl_up(inc, off, 64);
        if (lane >= off) inc += t;
    }
    if (lane == 63) woff[w] = inc;
    __syncthreads();
    int wpre = 0;
    if (w > 0) wpre += woff[0];
    if (w > 1) wpre += woff[1];
    if (w > 2) wpre += woff[2];
    int exc = boff[blockIdx.x] + wpre + inc - ts;
    int p0 = exc, p1 = exc + v0, p2 = p1 + v1, p3 = p2 + v2;
    if (i0     < N) { rowptr[i0]     = p0; cursor[i0]     = p0; }
    if (i0 + 1 < N) { rowptr[i0 + 1] = p1; cursor[i0 + 1] = p1; }
    if (i0 + 2 < N) { rowptr[i0 + 2] = p2; cursor[i0 + 2] = p2; }
    if (i0 + 3 < N) { rowptr[i0 + 3] = p3; cursor[i0 + 3] = p3; }
}

__global__ __launch_bounds__(256) void fill_kernel(
    const int* __restrict__ src, const int* __restrict__ dst,
    int* __restrict__ cursor, int* __restrict__ perm, int E)
{
    int e = blockIdx.x * blockDim.x + threadIdx.x;
    if (e >= E) return;
    int pos = atomicAdd(&cursor[dst[e]], 1);
    perm[pos] = src[e];
}

// ---------------- weight prep (both layers fused): Wt[col][k] hi/lo bf16 ----
// q columns (c<128) are pre-scaled by 1/sqrt(32)*log2(e): attention logits
// come out of the projection already in log2 domain -> attn uses raw v_exp_f32
// with no per-edge scale multiply.
__global__ __launch_bounds__(128) void wprep_all(
    const float* __restrict__ wq1, const float* __restrict__ bq1,
    const float* __restrict__ wk1, const float* __restrict__ bk1,
    const float* __restrict__ wv1, const float* __restrict__ bv1,
    const float* __restrict__ ws1, const float* __restrict__ bs1,
    const float* __restrict__ wq2, const float* __restrict__ bq2,
    const float* __restrict__ wk2, const float* __restrict__ bk2,
    const float* __restrict__ wv2, const float* __restrict__ bv2,
    const float* __restrict__ ws2, const float* __restrict__ bs2,
    unsigned short* __restrict__ wt1h, unsigned short* __restrict__ wt1l,
    float* __restrict__ bias1,
    unsigned short* __restrict__ wt2h, unsigned short* __restrict__ wt2l,
    float* __restrict__ bias2)
{
    const int layer = (blockIdx.x >= 416) ? 1 : 0;
    const int c = blockIdx.x - layer * 416;
    const int t = threadIdx.x;
    const int L = layer ? 32 : 128;
    if (t >= L) return;
    const float* w; const float* b; int cc, ncols;
    if (c < 384) {
        int m = c >> 7; cc = c & 127; ncols = 128;
        if (layer == 0) {
            w = (m == 0) ? wq1 : ((m == 1) ? wk1 : wv1);
            b = (m == 0) ? bq1 : ((m == 1) ? bk1 : bv1);
        } else {
            w = (m == 0) ? wq2 : ((m == 1) ? wk2 : wv2);
            b = (m == 0) ? bq2 : ((m == 1) ? bk2 : bv2);
        }
    } else {
        cc = c - 384; ncols = 32;
        w = layer ? ws2 : ws1; b = layer ? bs2 : bs1;
    }
    unsigned short* wh = layer ? wt2h : wt1h;
    unsigned short* wl = layer ? wt2l : wt1l;
    float* bias = layer ? bias2 : bias1;
    // 1/sqrt(32) * log2(e): fold softmax scale + exp->exp2 conversion into q
    const float QSCL = 0.17677669529663687f * 1.4426950408889634f;
    const float f = (c < 128) ? QSCL : 1.0f;
    float val = w[t * ncols + cc] * f;
    unsigned short h = f2bf(val);
    wh[c * L + t] = h;
    wl[c * L + t] = f2bf(val - bf2f(h));
    if (t == 0) bias[c] = b[cc] * f;
}

// ---------------- K1: MFMA projection, A-stationary, coalesced stores -------
// (unchanged from R9/R11 — see comments there)
template <int L>
__global__ __launch_bounds__(256) void proj_mfma(
    const float* __restrict__ xin,
    const unsigned short* __restrict__ wt_hi,
    const unsigned short* __restrict__ wt_lo,
    const float* __restrict__ bias,
    float* __restrict__ q, unsigned short* __restrict__ kvp,
    float* __restrict__ skip, int N)
{
    constexpr int LP = L + 8;          // ushort pad
    constexpr int KS = L / 32;
    constexpr int SI = (32 * (L / 4)) / 256;
    __shared__ unsigned short xh[2][32 * LP];
    __shared__ unsigned short xl[2][32 * LP];
    __shared__ float scr[4][32 * 36];
    const int tid = threadIdx.x, lane = tid & 63, w = tid >> 6;
    const int li = lane & 15, quad = lane >> 4;
    const int slot = __builtin_amdgcn_readfirstlane(blockIdx.y * 4 + w);
    const bool hasT = slot < 13;

    int t0 = 24, t1 = 25;
    if (slot < 4)       { t0 = slot * 2; t1 = t0 + 1; }
    else if (slot < 12) { t0 = 4 + slot; t1 = 12 + slot; }   // k=8+i, v=16+i

    short8 Ah[2][KS], Al[2][KS];
    float bias_r[2][4];
    if (hasT) {
#pragma unroll
        for (int ti = 0; ti < 2; ti++) {
            int tt = ti ? t1 : t0;
#pragma unroll
            for (int ks = 0; ks < KS; ks++) {
                long off = (long)(tt * 16 + li) * L + ks * 32 + quad * 8;
                Ah[ti][ks] = *(const short8*)(wt_hi + off);
                Al[ti][ks] = *(const short8*)(wt_lo + off);
            }
#pragma unroll
            for (int r = 0; r < 4; r++)
                bias_r[ti][r] = bias[tt * 16 + quad * 4 + r];
        }
    }

    const int nb0 = blockIdx.x * 256;
    float* myscr = scr[w];
    unsigned int* su = (unsigned int*)myscr;

    float4 xv[SI];
    auto issue_loads = [&](int c) {
#pragma unroll
        for (int s = 0; s < SI; s++) {
            int f = s * 256 + tid;
            int row = f / (L / 4), c4 = (f - row * (L / 4)) * 4;
            int n = nb0 + c * 32 + row;
            xv[s] = (n < N) ? *(const float4*)(xin + (long)n * L + c4)
                            : make_float4(0.f, 0.f, 0.f, 0.f);
        }
    };
    auto cvt_store = [&](int buf) {
#pragma unroll
        for (int s = 0; s < SI; s++) {
            int f = s * 256 + tid;
            int row = f / (L / 4), c4 = (f - row * (L / 4)) * 4;
            unsigned short h0 = f2bf(xv[s].x), h1 = f2bf(xv[s].y),
                           h2 = f2bf(xv[s].z), h3 = f2bf(xv[s].w);
            ushort4v hs = {h0, h1, h2, h3};
            ushort4v ls = {f2bf(xv[s].x - bf2f(h0)), f2bf(xv[s].y - bf2f(h1)),
                           f2bf(xv[s].z - bf2f(h2)), f2bf(xv[s].w - bf2f(h3))};
            *(ushort4v*)(xh[buf] + row * LP + c4) = hs;
            *(ushort4v*)(xl[buf] + row * LP + c4) = ls;
        }
    };

    issue_loads(0);
    cvt_store(0);
    __syncthreads();

    for (int c = 0; c < 8; c++) {
        if (c < 7) issue_loads(c + 1);
        const int n0c = nb0 + c * 32;
        if (hasT) {
            const int buf = c & 1;
#pragma unroll
            for (int half = 0; half < 2; half++) {
                short8 Bh[KS], Bl[KS];
#pragma unroll
                for (int ks = 0; ks < KS; ks++) {
                    int off = (half * 16 + li) * LP + ks * 32 + quad * 8;
                    Bh[ks] = *(const short8*)(xh[buf] + off);
                    Bl[ks] = *(const short8*)(xl[buf] + off);
                }
                floatx4 accv[2];
#pragma unroll
                for (int ti = 0; ti < 2; ti++) {
                    floatx4 acc = {0.f, 0.f, 0.f, 0.f};
#pragma unroll
                    for (int ks = 0; ks < KS; ks++) {
                        acc = __builtin_amdgcn_mfma_f32_16x16x32_bf16(Ah[ti][ks], Bh[ks], acc, 0, 0, 0);
                        acc = __builtin_amdgcn_mfma_f32_16x16x32_bf16(Ah[ti][ks], Bl[ks], acc, 0, 0, 0);
                        acc = __builtin_amdgcn_mfma_f32_16x16x32_bf16(Al[ti][ks], Bh[ks], acc, 0, 0, 0);
                    }
#pragma unroll
                    for (int r = 0; r < 4; r++) acc[r] += bias_r[ti][r];
                    accv[ti] = acc;
                }
                const int row = half * 16 + li;
                if (slot < 4 || slot == 12) {
                    *(floatx4*)(myscr + row * 36 + quad * 4)      = accv[0];
                    *(floatx4*)(myscr + row * 36 + 16 + quad * 4) = accv[1];
                } else {
                    unsigned int k01 = (unsigned int)f2bf(accv[0][0]) | ((unsigned int)f2bf(accv[0][1]) << 16);
                    unsigned int k23 = (unsigned int)f2bf(accv[0][2]) | ((unsigned int)f2bf(accv[0][3]) << 16);
                    unsigned int v01 = (unsigned int)f2bf(accv[1][0]) | ((unsigned int)f2bf(accv[1][1]) << 16);
                    unsigned int v23 = (unsigned int)f2bf(accv[1][2]) | ((unsigned int)f2bf(accv[1][3]) << 16);
                    uint4 pk = make_uint4(k01, v01, k23, v23);
                    *(uint4*)(su + row * 20 + quad * 4) = pk;
                }
            }
            if (slot < 4) {
#pragma unroll
                for (int it = 0; it < 4; it++) {
                    int idx = it * 64 + lane;
                    int nl = idx >> 3, seg = idx & 7;
                    int node = n0c + nl;
                    if (node < N) {
                        floatx4 vv = *(floatx4*)(myscr + nl * 36 + seg * 4);
                        *(floatx4*)(q + (long)node * 128 + slot * 32 + seg * 4) = vv;
                    }
                }
            } else if (slot == 12) {
#pragma unroll
                for (int it = 0; it < 4; it++) {
                    int idx = it * 64 + lane;
                    int nl = idx >> 3, seg = idx & 7;
                    int node = n0c + nl;
                    if (node < N) {
                        floatx4 vv = *(floatx4*)(myscr + nl * 36 + seg * 4);
                        *(floatx4*)(skip + (long)node * 32 + seg * 4) = vv;
                    }
                }
            } else {
                const int i = slot - 4;
#pragma unroll
                for (int it = 0; it < 2; it++) {
                    int idx = it * 64 + lane;
                    int nl = idx >> 2, part = idx & 3;
                    int node = n0c + nl;
                    if (node < N) {
                        uint4 vv = *(uint4*)(su + nl * 20 + part * 4);
                        *(uint4*)((unsigned int*)(kvp + (long)node * 256) + i * 16 + part * 4) = vv;
                    }
                }
            }
        }
        __syncthreads();
        if (c < 7) cvt_store((c + 1) & 1);
        __syncthreads();
    }
}

// ---------------- K2: fused attention, software-pipelined gathers ----------
// Wave = 1 dst node. lane = [eh:1][head:2][g:3]; lane owns dims hh*32+4g..+3.
// VALU-issue-bound (rocprof: VALUBusy ~80%, Mfma 0, LDS-conflict 0) -> this
// revision cuts per-edge instructions:
//  * logits arrive pre-scaled by 1/sqrt(32)*log2e (folded into wq/bq) ->
//    raw v_exp_f32 via EXP2F, no per-edge scale muls
//  * 32-bit offset addressing for kv/perm gathers (no 64-bit carry chains)
//  * p-reduction via DPP butterflies (no ds_bpermute, no lgkmcnt waits)
//  * per-node bsafe clamp replaces the per-prefetch i<E check
//  * unmasked main loop (j+4 <= nmin) + masked tail loop share the pipeline
template <bool FUSE_CLS>
__global__ __launch_bounds__(256) void attn_kernel(
    const float* __restrict__ q, const unsigned short* __restrict__ kvp,
    const int* __restrict__ rowptr, const int* __restrict__ perm,
    const float* __restrict__ skip, float* __restrict__ h,
    const float* __restrict__ wc, const float* __restrict__ bc,
    float* __restrict__ out, int N, int E)
{
    __shared__ float hrow[4][32];
    const int wid = (blockIdx.x * 256 + threadIdx.x) >> 6;
    const int wv = (threadIdx.x >> 6) & 3;
    const int lane = threadIdx.x & 63;
    if (wid >= N) return;
    const int d = __builtin_amdgcn_readfirstlane(wid);
    const int eh = lane >> 5;
    const int sl = lane & 31;
    const int hh = sl >> 3;
    const int g  = sl & 7;
    const unsigned dby = (unsigned)(hh * 64 + g * 8) * 2u;   // byte offset in 512B row
    const char* __restrict__ kvb = (const char*)kvp;
    const float4 q4 = *(const float4*)(q + (long)d * 128 + hh * 32 + g * 4);
    const int beg = rowptr[d], end = rowptr[d + 1];
    const int n = end - beg;
    const int na = (n + 1) >> 1;          // larger half (eh=0)
    const int nmin = n - na;              // smaller half (eh=1)
    const int my_off = beg + (eh ? na : 0);
    const int my_cnt = eh ? nmin : na;
    const int bsafe = (beg < E) ? beg : (E - 1);   // safe perm index for pads
    float m = -INFINITY, den = 0.f;
    float o0 = 0.f, o1 = 0.f, o2 = 0.f, o3 = 0.f;

    auto eidx = [&](int j) -> unsigned {
        return (unsigned)((j < my_cnt) ? my_off + j : bsafe);
    };
    auto kvld = [&](int s) -> uint4 {
        return *(const uint4*)(kvb + ((((unsigned)s) << 9) + dby));
    };

    // pipeline prime: perm for j=0..7, kv for j=0..3
    int P0 = perm[eidx(4)], P1 = perm[eidx(5)], P2 = perm[eidx(6)], P3 = perm[eidx(7)];
    uint4 A0 = kvld(perm[eidx(0)]), A1 = kvld(perm[eidx(1)]),
          A2 = kvld(perm[eidx(2)]), A3 = kvld(perm[eidx(3)]);

    int j = 0;
    auto step = [&](auto mc) {
        constexpr bool MASKED = decltype(mc)::value;
        // prefetch: kv for j+4 (via P), perm for j+8
        uint4 B0 = kvld(P0), B1 = kvld(P1), B2 = kvld(P2), B3 = kvld(P3);
        const int NP0 = perm[eidx(j + 8)],  NP1 = perm[eidx(j + 9)];
        const int NP2 = perm[eidx(j + 10)], NP3 = perm[eidx(j + 11)];

        float p0 = q4.x * blo(A0.x) + q4.y * bhi(A0.x) + q4.z * blo(A0.z) + q4.w * bhi(A0.z);
        float p1 = q4.x * blo(A1.x) + q4.y * bhi(A1.x) + q4.z * blo(A1.z) + q4.w * bhi(A1.z);
        float p2 = q4.x * blo(A2.x) + q4.y * bhi(A2.x) + q4.z * blo(A2.z) + q4.w * bhi(A2.z);
        float p3 = q4.x * blo(A3.x) + q4.y * bhi(A3.x) + q4.z * blo(A3.z) + q4.w * bhi(A3.z);
        p0 = red8(p0); p1 = red8(p1); p2 = red8(p2); p3 = red8(p3);
        if (MASKED) {
            p0 = (j + 0 < my_cnt) ? p0 : -INFINITY;
            p1 = (j + 1 < my_cnt) ? p1 : -INFINITY;
            p2 = (j + 2 < my_cnt) ? p2 : -INFINITY;
            p3 = (j + 3 < my_cnt) ? p3 : -INFINITY;
        }
        const float mb = fmaxf(fmaxf(p0, p1), fmaxf(p2, p3));
        const float nm = MASKED ? fmaxf(fmaxf(m, mb), -1e30f) : fmaxf(m, mb);
        const float sc = EXP2F(m - nm);
        const float w0 = EXP2F(p0 - nm), w1 = EXP2F(p1 - nm);
        const float w2 = EXP2F(p2 - nm), w3 = EXP2F(p3 - nm);
        den = den * sc + ((w0 + w1) + (w2 + w3));
        o0 = o0 * sc + w0 * blo(A0.y) + w1 * blo(A1.y) + w2 * blo(A2.y) + w3 * blo(A3.y);
        o1 = o1 * sc + w0 * bhi(A0.y) + w1 * bhi(A1.y) + w2 * bhi(A2.y) + w3 * bhi(A3.y);
        o2 = o2 * sc + w0 * blo(A0.w) + w1 * blo(A1.w) + w2 * blo(A2.w) + w3 * blo(A3.w);
        o3 = o3 * sc + w0 * bhi(A0.w) + w1 * bhi(A1.w) + w2 * bhi(A2.w) + w3 * bhi(A3.w);
        m = nm;
        A0 = B0; A1 = B1; A2 = B2; A3 = B3;
        P0 = NP0; P1 = NP1; P2 = NP2; P3 = NP3;
    };
    for (; j + 4 <= nmin; j += 4) step(BC<false>{});   // all 8 slots valid
    for (; j < na; j += 4)       step(BC<true>{});     // masked tail

    // merge the two halves (shfl_xor 32)
    {
        const float mo = __shfl_xor(m, 32);
        const float dn = __shfl_xor(den, 32);
        const float b0 = __shfl_xor(o0, 32);
        const float b1 = __shfl_xor(o1, 32);
        const float b2 = __shfl_xor(o2, 32);
        const float b3 = __shfl_xor(o3, 32);
        const float nm = fmaxf(fmaxf(m, mo), -1e30f);
        const float sa = EXP2F(m - nm);
        const float sb = EXP2F(mo - nm);
        den = den * sa + dn * sb;
        o0 = o0 * sa + b0 * sb;
        o1 = o1 * sa + b1 * sb;
        o2 = o2 * sa + b2 * sb;
        o3 = o3 * sa + b3 * sb;
    }
    const float inv = 1.f / (den + 1e-16f);
    o0 *= inv; o1 *= inv; o2 *= inv; o3 *= inv;
    // head mean: sum over head groups (xor 8 via DPP row_ror:8, then xor 16), /4
    o0 = xor8add(o0); o1 = xor8add(o1);
    o2 = xor8add(o2); o3 = xor8add(o3);
    o0 += __shfl_xor(o0, 16); o1 += __shfl_xor(o1, 16);
    o2 += __shfl_xor(o2, 16); o3 += __shfl_xor(o3, 16);

    if (lane < 8) {
        float4 sk = *(const float4*)(skip + (long)d * 32 + g * 4);
        float r0 = 0.25f * o0 + sk.x;
        float r1 = 0.25f * o1 + sk.y;
        float r2 = 0.25f * o2 + sk.z;
        float r3 = 0.25f * o3 + sk.w;
        r0 = r0 > 0.f ? r0 : 0.f;
        r1 = r1 > 0.f ? r1 : 0.f;
        r2 = r2 > 0.f ? r2 : 0.f;
        r3 = r3 > 0.f ? r3 : 0.f;
        if (FUSE_CLS) {
            *(float4*)&hrow[wv][g * 4] = make_float4(r0, r1, r2, r3);
        } else {
            *(float4*)(h + (long)d * 32 + g * 4) = make_float4(r0, r1, r2, r3);
        }
    }
    if (FUSE_CLS) {
        __builtin_amdgcn_wave_barrier();   // wave-internal LDS ordering (no HW cost)
        if (lane < 40) {
            float acc = bc[lane];
#pragma unroll
            for (int l = 0; l < 32; ++l)
                acc = fmaf(hrow[wv][l], wc[l * 40 + lane], acc);
            out[(long)d * 40 + lane] = acc;
        }
    }
}

extern "C" void kernel_launch(void* const* d_in, const int* in_sizes, int n_in,
                              void* d_out, int out_size, void* d_ws, size_t ws_size,
                              hipStream_t stream)
{
    const float* x   = (const float*)d_in[0];
    const int* ei    = (const int*)d_in[1];
    const float* wq1 = (const float*)d_in[2];  const float* bq1 = (const float*)d_in[3];
    const float* wk1 = (const float*)d_in[4];  const float* bk1 = (const float*)d_in[5];
    const float* wv1 = (const float*)d_in[6];  const float* bv1 = (const float*)d_in[7];
    const float* ws1 = (const float*)d_in[8];  const float* bs1 = (const float*)d_in[9];
    const float* wq2 = (const float*)d_in[10]; const float* bq2 = (const float*)d_in[11];
    const float* wk2 = (const float*)d_in[12]; const float* bk2 = (const float*)d_in[13];
    const float* wv2 = (const float*)d_in[14]; const float* bv2 = (const float*)d_in[15];
    const float* ws2 = (const float*)d_in[16]; const float* bs2 = (const float*)d_in[17];
    const float* wc  = (const float*)d_in[18]; const float* bc  = (const float*)d_in[19];

    const int N = in_sizes[0] / 128;   // 50000
    const int E = in_sizes[1] / 2;     // 800000
    const int* src = ei;
    const int* dst = ei + E;

    // workspace layout (bytes, 256-aligned chunks)
    char* p = (char*)d_ws;
    auto take = [&](size_t bytes) { char* r = p; p += (bytes + 255) & ~(size_t)255; return r; };
    float* q             = (float*)take((size_t)N * 128 * 4);
    unsigned short* kvp  = (unsigned short*)take((size_t)N * 256 * 2);
    float* skip          = (float*)take((size_t)N * 32 * 4);
    float* h1            = (float*)take((size_t)N * 32 * 4);
    unsigned short* wt1h = (unsigned short*)take(416 * 128 * 2);
    unsigned short* wt1l = (unsigned short*)take(416 * 128 * 2);
    unsigned short* wt2h = (unsigned short*)take(416 * 32 * 2);
    unsigned short* wt2l = (unsigned short*)take(416 * 32 * 2);
    float* bias1         = (float*)take(416 * 4);
    float* bias2         = (float*)take(416 * 4);
    int* deg             = (int*)take((size_t)N * 4);
    int* rowptr          = (int*)take((size_t)(N + 1) * 4);
    int* cursor          = (int*)take((size_t)N * 4);
    int* perm            = (int*)take((size_t)E * 4);
    int* bsum            = (int*)take(64 * 4);
    int* boff            = (int*)take(64 * 4);

    const dim3 projGrid((N + 255) / 256, 4);
    const int eGrid    = (E + 255) / 256;
    const int attnGrid = (N + 3) / 4;          // 4 waves/block
    const int nb       = (N + 1023) / 1024;    // <= 64

    // ---------------- weight prep + CSR build ----------------
    wprep_all<<<832, 128, 0, stream>>>(wq1, bq1, wk1, bk1, wv1, bv1, ws1, bs1,
                                       wq2, bq2, wk2, bk2, wv2, bv2, ws2, bs2,
                                       wt1h, wt1l, bias1, wt2h, wt2l, bias2);
    hipMemsetAsync(deg, 0, (size_t)N * 4, stream);
    hist_kernel<<<eGrid, 256, 0, stream>>>(dst, deg, E);
    scan_part<<<nb, 256, 0, stream>>>(deg, bsum, N);
    scan_tops<<<1, 64, 0, stream>>>(bsum, boff, rowptr, nb, N);
    scan_final<<<nb, 256, 0, stream>>>(deg, boff, rowptr, cursor, N);
    fill_kernel<<<eGrid, 256, 0, stream>>>(src, dst, cursor, perm, E);

    // ---------------- layer 1 ----------------
    proj_mfma<128><<<projGrid, 256, 0, stream>>>(x, wt1h, wt1l, bias1, q, kvp, skip, N);
    attn_kernel<false><<<attnGrid, 256, 0, stream>>>(q, kvp, rowptr, perm, skip, h1,
                                                     wc, bc, (float*)d_out, N, E);

    // ---------------- layer 2 (classifier fused into attn epilogue) --------
    proj_mfma<32><<<projGrid, 256, 0, stream>>>(h1, wt2h, wt2l, bias2, q, kvp, skip, N);
    attn_kernel<true><<<attnGrid, 256, 0, stream>>>(q, kvp, rowptr, perm, skip, h1,
                                                    wc, bc, (float*)d_out, N, E);
}